// Round 1
// baseline (3611.003 us; speedup 1.0000x reference)
//
#include <hip/hip_runtime.h>

// LSTM: B=1024, T=128, I=128, H=1024, O=64
// Strategy: bf16 MFMA GEMM per timestep (M=1024, N=4096 gates, K=1152=[x_t|h]),
// gate-interleaved weight layout so the LSTM cell update is in-lane in the
// MFMA epilogue. h double-buffered bf16; c fp32 (block-private per tile).

#define B_DIM 1024
#define H_DIM 1024
#define I_DIM 128
#define T_DIM 128
#define XROW  (T_DIM * I_DIM)   // 16384
#define KDIM  (I_DIM + H_DIM)   // 1152
#define GDIM  (4 * H_DIM)       // 4096
#define O_DIM 64

typedef float f32x4 __attribute__((ext_vector_type(4)));
typedef short bf16x8 __attribute__((ext_vector_type(8)));
typedef unsigned short u16x8 __attribute__((ext_vector_type(8)));

__device__ __forceinline__ unsigned short f2bf(float f) {
    union { float f; unsigned int u; } v; v.f = f;
    unsigned int r = v.u + 0x7fffu + ((v.u >> 16) & 1u);  // RNE
    return (unsigned short)(r >> 16);
}
__device__ __forceinline__ float bf2f(unsigned short b) {
    union { unsigned int u; float f; } v; v.u = ((unsigned int)b) << 16;
    return v.f;
}
__device__ __forceinline__ float sigm(float x) { return 1.f / (1.f + __expf(-x)); }
__device__ __forceinline__ float tanh_fast(float x) { return 2.f / (1.f + __expf(-2.f * x)) - 1.f; }

// ---- prep: fp32 x -> bf16 ----
__global__ void conv_x(const float* __restrict__ x, unsigned short* __restrict__ xb) {
    size_t i = ((size_t)blockIdx.x * 256 + threadIdx.x) * 8;  // 8192 blocks covers 16777216
    float4 v0 = *(const float4*)(x + i);
    float4 v1 = *(const float4*)(x + i + 4);
    u16x8 o;
    o[0] = f2bf(v0.x); o[1] = f2bf(v0.y); o[2] = f2bf(v0.z); o[3] = f2bf(v0.w);
    o[4] = f2bf(v1.x); o[5] = f2bf(v1.y); o[6] = f2bf(v1.z); o[7] = f2bf(v1.w);
    *(u16x8*)(xb + i) = o;
}

// ---- prep: build gate-interleaved W'' [4096 x 1152] bf16 and combined bias ----
// row r: nb=r>>7, q=r&127, wh=q>>6, w=q&63, gate=w>>4, jl=w&15
// orig gate row = gate*1024 + nb*32 + wh*16 + jl   (h-dim j = nb*32+wh*16+jl)
__global__ void build_w(const float* __restrict__ w_ih, const float* __restrict__ w_hh,
                        const float* __restrict__ b_ih, const float* __restrict__ b_hh,
                        unsigned short* __restrict__ W, float* __restrict__ bias) {
    int r = blockIdx.x;
    int nb = r >> 7, q = r & 127;
    int wh = q >> 6, w = q & 63;
    int gate = w >> 4, jl = w & 15;
    int orig = gate * 1024 + nb * 32 + wh * 16 + jl;
    for (int k = threadIdx.x; k < KDIM; k += 256) {
        float v = (k < I_DIM) ? w_ih[(size_t)orig * I_DIM + k]
                              : w_hh[(size_t)orig * H_DIM + (k - I_DIM)];
        W[(size_t)r * KDIM + k] = f2bf(v);
    }
    if (threadIdx.x == 0) bias[r] = b_ih[orig] + b_hh[orig];
}

// ---- prep: zero h0 (bf16) and c (fp32) ----
__global__ void zero_hc(unsigned short* __restrict__ h0, float* __restrict__ c) {
    int idx = blockIdx.x * 256 + threadIdx.x;  // 4096 blocks -> 1048576
    h0[idx] = 0;
    c[idx] = 0.f;
}

// ---- per-timestep: gates GEMM (128x128 tile) + fused LSTM cell epilogue ----
__global__ __launch_bounds__(256, 2)
void lstm_step(const unsigned short* __restrict__ xb,
               const unsigned short* __restrict__ W,
               const float* __restrict__ bias,
               const unsigned short* __restrict__ h_in,
               unsigned short* __restrict__ h_out,
               float* __restrict__ c_st,
               int t) {
    __shared__ __align__(16) unsigned short As[128 * 64];
    __shared__ __align__(16) unsigned short Bs[128 * 64];
    const int tid  = threadIdx.x;
    const int wv   = tid >> 6, lane = tid & 63;
    const int wmh  = wv >> 1, wnh = wv & 1;      // 2x2 wave grid over 128x128
    const int quad = lane >> 4, l16 = lane & 15;
    const int nb   = blockIdx.x, mb = blockIdx.y;

    f32x4 acc[4][4];
#pragma unroll
    for (int i = 0; i < 4; i++)
#pragma unroll
        for (int j = 0; j < 4; j++) acc[i][j] = f32x4{0.f, 0.f, 0.f, 0.f};

    const int arow = lane >> 3;        // row within 8-row chunk
    const int acol = (lane & 7) * 8;   // bf16 col offset (16B lanes)

    for (int ks = 0; ks < 18; ++ks) {
        const int kt = ks * 64;
#pragma unroll
        for (int c4 = 0; c4 < 4; ++c4) {
            const int row0 = wv * 32 + c4 * 8;
            const int row  = row0 + arow;
            const unsigned short* srcA =
                (kt < I_DIM)
                    ? xb  + (size_t)(mb * 128 + row) * XROW + t * I_DIM + kt + acol
                    : h_in + (size_t)(mb * 128 + row) * H_DIM + (kt - I_DIM) + acol;
            __builtin_amdgcn_global_load_lds(
                (const __attribute__((address_space(1))) void*)srcA,
                (__attribute__((address_space(3))) void*)(&As[row0 * 64]), 16, 0, 0);
            const unsigned short* srcB = W + (size_t)(nb * 128 + row) * KDIM + kt + acol;
            __builtin_amdgcn_global_load_lds(
                (const __attribute__((address_space(1))) void*)srcB,
                (__attribute__((address_space(3))) void*)(&Bs[row0 * 64]), 16, 0, 0);
        }
        __syncthreads();
#pragma unroll
        for (int kk = 0; kk < 64; kk += 32) {
            bf16x8 af[4], bfr[4];
#pragma unroll
            for (int mi = 0; mi < 4; mi++)
                af[mi] = *(const bf16x8*)&As[(wmh * 64 + mi * 16 + l16) * 64 + kk + quad * 8];
#pragma unroll
            for (int ni = 0; ni < 4; ni++)
                bfr[ni] = *(const bf16x8*)&Bs[(wnh * 64 + ni * 16 + l16) * 64 + kk + quad * 8];
#pragma unroll
            for (int mi = 0; mi < 4; mi++)
#pragma unroll
                for (int ni = 0; ni < 4; ni++)
                    acc[mi][ni] = __builtin_amdgcn_mfma_f32_16x16x32_bf16(
                        af[mi], bfr[ni], acc[mi][ni], 0, 0, 0);
        }
        __syncthreads();
    }

    // epilogue: ni == gate (0:i 1:f 2:g 3:o), all in-lane
    const int j   = nb * 32 + wnh * 16 + l16;
    const int bb  = nb * 128 + wnh * 64 + l16;
    const float bi = bias[bb +  0];
    const float bf_ = bias[bb + 16];
    const float bg = bias[bb + 32];
    const float bo = bias[bb + 48];
#pragma unroll
    for (int mi = 0; mi < 4; mi++) {
#pragma unroll
        for (int r = 0; r < 4; r++) {
            const int brow = mb * 128 + wmh * 64 + mi * 16 + quad * 4 + r;
            const float gi = acc[mi][0][r] + bi;
            const float gf = acc[mi][1][r] + bf_;
            const float gg = acc[mi][2][r] + bg;
            const float go = acc[mi][3][r] + bo;
            const size_t idx = (size_t)brow * H_DIM + j;
            const float cn = sigm(gf) * c_st[idx] + sigm(gi) * tanh_fast(gg);
            c_st[idx] = cn;
            h_out[idx] = f2bf(sigm(go) * tanh_fast(cn));
        }
    }
}

// ---- final projection: out[b,o] = h[b,:] . w_fc[o,:] + b_fc[o] ----
__global__ void proj(const unsigned short* __restrict__ h,
                     const float* __restrict__ w_fc,
                     const float* __restrict__ b_fc,
                     float* __restrict__ out) {
    __shared__ float hs[H_DIM];
    const int b = blockIdx.x, tid = threadIdx.x;  // 64 threads = 1 wave
    for (int k = tid; k < H_DIM; k += 64) hs[k] = bf2f(h[(size_t)b * H_DIM + k]);
    __syncthreads();
    float s = b_fc[tid];
    const float* wr = w_fc + (size_t)tid * H_DIM;
#pragma unroll 8
    for (int k = 0; k < H_DIM; ++k) s += hs[k] * wr[k];
    out[(size_t)b * O_DIM + tid] = s;
}

extern "C" void kernel_launch(void* const* d_in, const int* in_sizes, int n_in,
                              void* d_out, int out_size, void* d_ws, size_t ws_size,
                              hipStream_t stream) {
    const float* x    = (const float*)d_in[0];
    const float* w_ih = (const float*)d_in[1];
    const float* w_hh = (const float*)d_in[2];
    const float* b_ih = (const float*)d_in[3];
    const float* b_hh = (const float*)d_in[4];
    const float* w_fc = (const float*)d_in[5];
    const float* b_fc = (const float*)d_in[6];
    float* out = (float*)d_out;

    char* ws = (char*)d_ws;
    size_t off = 0;
    unsigned short* xb = (unsigned short*)(ws + off); off += (size_t)B_DIM * XROW * 2;      // 33.6 MB
    unsigned short* W  = (unsigned short*)(ws + off); off += (size_t)GDIM * KDIM * 2;       // 9.4 MB
    float* bias        = (float*)(ws + off);          off += (size_t)GDIM * 4;              // 16 KB
    unsigned short* h0 = (unsigned short*)(ws + off); off += (size_t)B_DIM * H_DIM * 2;     // 2 MB
    unsigned short* h1 = (unsigned short*)(ws + off); off += (size_t)B_DIM * H_DIM * 2;     // 2 MB
    float* c           = (float*)(ws + off);          off += (size_t)B_DIM * H_DIM * 4;     // 4 MB

    conv_x<<<8192, 256, 0, stream>>>(x, xb);
    build_w<<<GDIM, 256, 0, stream>>>(w_ih, w_hh, b_ih, b_hh, W, bias);
    zero_hc<<<4096, 256, 0, stream>>>(h0, c);

    for (int t = 0; t < T_DIM; ++t) {
        const unsigned short* hin = (t & 1) ? h1 : h0;
        unsigned short* hout      = (t & 1) ? h0 : h1;
        lstm_step<<<dim3(32, 8), 256, 0, stream>>>(xb, W, bias, hin, hout, c, t);
    }
    // t=127 wrote h0
    proj<<<B_DIM, 64, 0, stream>>>(h0, w_fc, b_fc, out);
}

// Round 2
// 2450.327 us; speedup vs baseline: 1.4737x; 1.4737x over previous
//
#include <hip/hip_runtime.h>

// LSTM: B=1024, T=128, I=128, H=1024, O=64
// R1: XOR-swizzled LDS layout (kills 16-way bank conflicts on ds_read_b128)
//     + M-split 64x128 tiles, grid 512 = 2 blocks/CU for latency hiding.
// Gate-interleaved W rows so the LSTM cell update is in-lane in the epilogue.

#define B_DIM 1024
#define H_DIM 1024
#define I_DIM 128
#define T_DIM 128
#define XROW  (T_DIM * I_DIM)   // 16384
#define KDIM  (I_DIM + H_DIM)   // 1152
#define GDIM  (4 * H_DIM)       // 4096
#define O_DIM 64

typedef float f32x4 __attribute__((ext_vector_type(4)));
typedef short bf16x8 __attribute__((ext_vector_type(8)));
typedef unsigned short u16x8 __attribute__((ext_vector_type(8)));

__device__ __forceinline__ unsigned short f2bf(float f) {
    union { float f; unsigned int u; } v; v.f = f;
    unsigned int r = v.u + 0x7fffu + ((v.u >> 16) & 1u);  // RNE
    return (unsigned short)(r >> 16);
}
__device__ __forceinline__ float bf2f(unsigned short b) {
    union { unsigned int u; float f; } v; v.u = ((unsigned int)b) << 16;
    return v.f;
}
__device__ __forceinline__ float sigm(float x) { return 1.f / (1.f + __expf(-x)); }
__device__ __forceinline__ float tanh_fast(float x) { return 2.f / (1.f + __expf(-2.f * x)) - 1.f; }

// ---- prep: fp32 x -> bf16 ----
__global__ void conv_x(const float* __restrict__ x, unsigned short* __restrict__ xb) {
    size_t i = ((size_t)blockIdx.x * 256 + threadIdx.x) * 8;
    float4 v0 = *(const float4*)(x + i);
    float4 v1 = *(const float4*)(x + i + 4);
    u16x8 o;
    o[0] = f2bf(v0.x); o[1] = f2bf(v0.y); o[2] = f2bf(v0.z); o[3] = f2bf(v0.w);
    o[4] = f2bf(v1.x); o[5] = f2bf(v1.y); o[6] = f2bf(v1.z); o[7] = f2bf(v1.w);
    *(u16x8*)(xb + i) = o;
}

// ---- prep: gate-interleaved W'' [4096 x 1152] bf16 + combined bias ----
// row r: nb=r>>7, q=r&127, wh=q>>6, w=q&63, gate=w>>4, jl=w&15
// orig gate row = gate*1024 + nb*32 + wh*16 + jl
__global__ void build_w(const float* __restrict__ w_ih, const float* __restrict__ w_hh,
                        const float* __restrict__ b_ih, const float* __restrict__ b_hh,
                        unsigned short* __restrict__ W, float* __restrict__ bias) {
    int r = blockIdx.x;
    int nb = r >> 7, q = r & 127;
    int wh = q >> 6, w = q & 63;
    int gate = w >> 4, jl = w & 15;
    int orig = gate * 1024 + nb * 32 + wh * 16 + jl;
    for (int k = threadIdx.x; k < KDIM; k += 256) {
        float v = (k < I_DIM) ? w_ih[(size_t)orig * I_DIM + k]
                              : w_hh[(size_t)orig * H_DIM + (k - I_DIM)];
        W[(size_t)r * KDIM + k] = f2bf(v);
    }
    if (threadIdx.x == 0) bias[r] = b_ih[orig] + b_hh[orig];
}

__global__ void zero_hc(unsigned short* __restrict__ h0, float* __restrict__ c) {
    int idx = blockIdx.x * 256 + threadIdx.x;
    h0[idx] = 0;
    c[idx] = 0.f;
}

// ---- per-timestep: 64x128 tile GEMM + fused LSTM cell epilogue ----
// LDS layout XOR-swizzled: phys group gphys of row r holds logical group
// gphys ^ (r&7). Staging permutes SOURCE addresses (LDS side of
// global_load_lds must stay wave-uniform-base + lane*16).
__global__ __launch_bounds__(256, 2)
void lstm_step(const unsigned short* __restrict__ xb,
               const unsigned short* __restrict__ W,
               const float* __restrict__ bias,
               const unsigned short* __restrict__ h_in,
               unsigned short* __restrict__ h_out,
               float* __restrict__ c_st,
               int t) {
    __shared__ __align__(16) unsigned short As[64 * 64];
    __shared__ __align__(16) unsigned short Bs[128 * 64];
    const int tid  = threadIdx.x;
    const int wv   = tid >> 6, lane = tid & 63;
    const int wm   = wv >> 1, wn = wv & 1;      // 2x2 wave grid over 64x128
    const int quad = lane >> 4, l16 = lane & 15;
    const int l7   = l16 & 7;
    const int nb   = blockIdx.x, mb = blockIdx.y;

    f32x4 acc[2][4];
#pragma unroll
    for (int i = 0; i < 2; i++)
#pragma unroll
        for (int j = 0; j < 4; j++) acc[i][j] = f32x4{0.f, 0.f, 0.f, 0.f};

    const int arow = lane >> 3;              // 0..7: row within 8-row chunk
    const int ag   = lane & 7;               // physical 16B group this lane fills
    const int colperm = ((ag ^ arow) << 3);  // swizzled source column (bf16 units)

    for (int ks = 0; ks < 18; ++ks) {
        const int kt = ks * 64;
        // A tile: 64 rows x 64 cols, 2 chunks of 8 rows per wave
#pragma unroll
        for (int c4 = 0; c4 < 2; ++c4) {
            const int row0 = wv * 16 + c4 * 8;
            const int row  = row0 + arow;
            const unsigned short* srcA =
                (kt < I_DIM)
                    ? xb   + (size_t)(mb * 64 + row) * XROW + t * I_DIM + kt + colperm
                    : h_in + (size_t)(mb * 64 + row) * H_DIM + (kt - I_DIM) + colperm;
            __builtin_amdgcn_global_load_lds(
                (const __attribute__((address_space(1))) void*)srcA,
                (__attribute__((address_space(3))) void*)(&As[row0 * 64]), 16, 0, 0);
        }
        // B tile: 128 rows x 64 cols, 4 chunks of 8 rows per wave
#pragma unroll
        for (int c4 = 0; c4 < 4; ++c4) {
            const int row0 = wv * 32 + c4 * 8;
            const int row  = row0 + arow;
            const unsigned short* srcB =
                W + (size_t)(nb * 128 + row) * KDIM + kt + colperm;
            __builtin_amdgcn_global_load_lds(
                (const __attribute__((address_space(1))) void*)srcB,
                (__attribute__((address_space(3))) void*)(&Bs[row0 * 64]), 16, 0, 0);
        }
        __syncthreads();
#pragma unroll
        for (int kk = 0; kk < 64; kk += 32) {
            const int gb = kk >> 3;  // logical group base: 0 or 4
            bf16x8 af[2], bfr[4];
#pragma unroll
            for (int mi = 0; mi < 2; mi++) {
                const int r = wm * 32 + mi * 16 + l16;
                af[mi] = *(const bf16x8*)&As[r * 64 + (((gb + quad) ^ l7) << 3)];
            }
#pragma unroll
            for (int ni = 0; ni < 4; ni++) {
                const int r = wn * 64 + ni * 16 + l16;
                bfr[ni] = *(const bf16x8*)&Bs[r * 64 + (((gb + quad) ^ l7) << 3)];
            }
#pragma unroll
            for (int mi = 0; mi < 2; mi++)
#pragma unroll
                for (int ni = 0; ni < 4; ni++)
                    acc[mi][ni] = __builtin_amdgcn_mfma_f32_16x16x32_bf16(
                        af[mi], bfr[ni], acc[mi][ni], 0, 0, 0);
        }
        __syncthreads();
    }

    // epilogue: ni == gate (0:i 1:f 2:g 3:o), fully in-lane
    const int j  = nb * 32 + wn * 16 + l16;
    const int bb = nb * 128 + wn * 64 + l16;
    const float bi  = bias[bb +  0];
    const float bf_ = bias[bb + 16];
    const float bg  = bias[bb + 32];
    const float bo  = bias[bb + 48];
#pragma unroll
    for (int mi = 0; mi < 2; mi++) {
#pragma unroll
        for (int r = 0; r < 4; r++) {
            const int brow = mb * 64 + wm * 32 + mi * 16 + quad * 4 + r;
            const float gi = acc[mi][0][r] + bi;
            const float gf = acc[mi][1][r] + bf_;
            const float gg = acc[mi][2][r] + bg;
            const float go = acc[mi][3][r] + bo;
            const size_t idx = (size_t)brow * H_DIM + j;
            const float cn = sigm(gf) * c_st[idx] + sigm(gi) * tanh_fast(gg);
            c_st[idx] = cn;
            h_out[idx] = f2bf(sigm(go) * tanh_fast(cn));
        }
    }
}

// ---- final projection ----
__global__ void proj(const unsigned short* __restrict__ h,
                     const float* __restrict__ w_fc,
                     const float* __restrict__ b_fc,
                     float* __restrict__ out) {
    __shared__ float hs[H_DIM];
    const int b = blockIdx.x, tid = threadIdx.x;  // 64 threads = 1 wave
    for (int k = tid; k < H_DIM; k += 64) hs[k] = bf2f(h[(size_t)b * H_DIM + k]);
    __syncthreads();
    float s = b_fc[tid];
    const float* wr = w_fc + (size_t)tid * H_DIM;
#pragma unroll 8
    for (int k = 0; k < H_DIM; ++k) s += hs[k] * wr[k];
    out[(size_t)b * O_DIM + tid] = s;
}

extern "C" void kernel_launch(void* const* d_in, const int* in_sizes, int n_in,
                              void* d_out, int out_size, void* d_ws, size_t ws_size,
                              hipStream_t stream) {
    const float* x    = (const float*)d_in[0];
    const float* w_ih = (const float*)d_in[1];
    const float* w_hh = (const float*)d_in[2];
    const float* b_ih = (const float*)d_in[3];
    const float* b_hh = (const float*)d_in[4];
    const float* w_fc = (const float*)d_in[5];
    const float* b_fc = (const float*)d_in[6];
    float* out = (float*)d_out;

    char* ws = (char*)d_ws;
    size_t off = 0;
    unsigned short* xb = (unsigned short*)(ws + off); off += (size_t)B_DIM * XROW * 2;
    unsigned short* W  = (unsigned short*)(ws + off); off += (size_t)GDIM * KDIM * 2;
    float* bias        = (float*)(ws + off);          off += (size_t)GDIM * 4;
    unsigned short* h0 = (unsigned short*)(ws + off); off += (size_t)B_DIM * H_DIM * 2;
    unsigned short* h1 = (unsigned short*)(ws + off); off += (size_t)B_DIM * H_DIM * 2;
    float* c           = (float*)(ws + off);          off += (size_t)B_DIM * H_DIM * 4;

    conv_x<<<8192, 256, 0, stream>>>(x, xb);
    build_w<<<GDIM, 256, 0, stream>>>(w_ih, w_hh, b_ih, b_hh, W, bias);
    zero_hc<<<4096, 256, 0, stream>>>(h0, c);

    for (int t = 0; t < T_DIM; ++t) {
        const unsigned short* hin = (t & 1) ? h1 : h0;
        unsigned short* hout      = (t & 1) ? h0 : h1;
        lstm_step<<<dim3(32, 16), 256, 0, stream>>>(xb, W, bias, hin, hout, c, t);
    }
    // t=127 wrote h0
    proj<<<B_DIM, 64, 0, stream>>>(h0, w_fc, b_fc, out);
}